// Round 3
// baseline (89.038 us; speedup 1.0000x reference)
//
#include <hip/hip_runtime.h>
#include <stdint.h>

#define NROWS 8192
#define DIM 128

typedef __bf16 bf16x8 __attribute__((ext_vector_type(8)));
typedef float floatx4 __attribute__((ext_vector_type(4)));

// ---------- helpers ----------
static __device__ __forceinline__ unsigned short f2bf(float f) {
    unsigned int u = __float_as_uint(f);
    unsigned int r = (u + 0x7FFFu + ((u >> 16) & 1u)) >> 16;   // RNE
    return (unsigned short)r;
}

// XOR swizzle on linear uint4 index g (cols x 16 uint4 per col):
// breaks the 16-way bank-group conflict of the naive layout; swizzled
// access is 2-way = free (m136).
static __device__ __forceinline__ int swz(int g) {
    return (g & ~15) | ((g & 15) ^ ((g >> 4) & 7));
}

// ---------- kernel 1: normalize rows, emit bf16 a_hat + pos_dist + init max keys ----------
__global__ __launch_bounds__(256) void normalize_kernel(
    const float* __restrict__ anchor, const float* __restrict__ positive,
    unsigned short* __restrict__ a_hat, float* __restrict__ pos_ws,
    int* __restrict__ g_ws)
{
    const int wave = threadIdx.x >> 6;
    const int lane = threadIdx.x & 63;
    const int row  = blockIdx.x * 4 + wave;

    const float2* arow = (const float2*)(anchor   + row * DIM);
    const float2* prow = (const float2*)(positive + row * DIM);
    float2 a = arow[lane];
    float2 p = prow[lane];

    float sa  = a.x * a.x + a.y * a.y;
    float sp  = p.x * p.x + p.y * p.y;
    float sap = a.x * p.x + a.y * p.y;
    #pragma unroll
    for (int off = 32; off; off >>= 1) {
        sa  += __shfl_xor(sa,  off);
        sp  += __shfl_xor(sp,  off);
        sap += __shfl_xor(sap, off);
    }
    float na  = fmaxf(sqrtf(sa), 1e-12f);
    float npn = fmaxf(sqrtf(sp), 1e-12f);
    float inv = 1.0f / na;

    ushort2 pack;
    pack.x = f2bf(a.x * inv);
    pack.y = f2bf(a.y * inv);
    ((ushort2*)a_hat)[row * 64 + lane] = pack;

    if (lane == 0) {
        pos_ws[row] = 2.0f - 2.0f * sap / (na * npn);
        g_ws[row]   = 0x3F800000;   // key for g = -1  (key = 2+g = 1.0f)
    }
}

// ---------- kernel 2: fused gram row-max with label mask ----------
// grid = 512: blockIdx>>4 = row block (256 rows), blockIdx&15 = 512-col chunk.
// Wave strip = 64 rows (afrag[4][4] resident): each 1KB B-read feeds 4 MFMAs.
// B staged 64 cols (16 KB) per stage, double-buffered swizzled LDS shared by
// 4 waves; register prefetch of next stage; 1 barrier per 64-col stage.
__global__ __launch_bounds__(256, 2) void gram_kernel(
    const unsigned short* __restrict__ a_hat, const int* __restrict__ labels,
    int* __restrict__ g_ws)
{
    const int tid  = threadIdx.x;
    const int lane = tid & 63;
    const int wave = tid >> 6;
    const int quad = lane >> 4;
    const int l15  = lane & 15;

    const int rowBlock = blockIdx.x >> 4;     // 0..31
    const int nchunk   = blockIdx.x & 15;     // 0..15
    const int rowBase  = rowBlock * 256 + wave * 64;

    const uint4* A = (const uint4*)a_hat;     // row stride = 16 uint4 (256 B)

    __shared__ uint4 smem[2][1024];           // 2 x 16 KB

    // A fragments: lane holds A[m=l15][k = quad*8..+7] (+32 per kstep)
    bf16x8 afrag[4][4];
    #pragma unroll
    for (int s = 0; s < 4; ++s) {
        int r = rowBase + s * 16 + l15;
        #pragma unroll
        for (int k = 0; k < 4; ++k) {
            uint4 v = A[r * 16 + k * 4 + quad];
            afrag[s][k] = __builtin_bit_cast(bf16x8, v);
        }
    }

    // row labels for this lane's C-fragment rows: row = rowBase + s*16 + quad*4 + e
    int rlab[4][4];
    #pragma unroll
    for (int s = 0; s < 4; ++s)
        #pragma unroll
        for (int e = 0; e < 4; ++e)
            rlab[s][e] = labels[rowBase + s * 16 + quad * 4 + e];

    float gmax[4][4];
    #pragma unroll
    for (int s = 0; s < 4; ++s)
        #pragma unroll
        for (int e = 0; e < 4; ++e)
            gmax[s][e] = -4.0f;

    const int colBase = nchunk * 512;                 // 512 cols = 8 stages of 64
    const uint4* Gp = A + colBase * 16;               // stage st at Gp + st*1024

    // stage 0
    uint4 p0 = Gp[tid];
    uint4 p1 = Gp[tid + 256];
    uint4 p2 = Gp[tid + 512];
    uint4 p3 = Gp[tid + 768];
    smem[0][swz(tid)]       = p0;
    smem[0][swz(tid + 256)] = p1;
    smem[0][swz(tid + 512)] = p2;
    smem[0][swz(tid + 768)] = p3;
    __syncthreads();

    for (int st = 0; st < 8; ++st) {
        const int cur = st & 1;

        if (st < 7) {                                 // prefetch next stage
            const uint4* Gn = Gp + (st + 1) * 1024;
            p0 = Gn[tid];
            p1 = Gn[tid + 256];
            p2 = Gn[tid + 512];
            p3 = Gn[tid + 768];
        }

        const int C = colBase + st * 64;
        int clab[4];
        #pragma unroll
        for (int t = 0; t < 4; ++t)
            clab[t] = labels[C + t * 16 + l15];

        #pragma unroll
        for (int sub = 0; sub < 2; ++sub) {           // two 32-col subtiles
            bf16x8 bfrag[2][4];
            #pragma unroll
            for (int ns = 0; ns < 2; ++ns) {
                int c = sub * 32 + ns * 16 + l15;     // col within stage
                #pragma unroll
                for (int k = 0; k < 4; ++k) {
                    int g = c * 16 + k * 4 + quad;
                    bfrag[ns][k] = __builtin_bit_cast(bf16x8, smem[cur][swz(g)]);
                }
            }

            #pragma unroll
            for (int ms = 0; ms < 4; ++ms) {
                #pragma unroll
                for (int ns = 0; ns < 2; ++ns) {
                    floatx4 acc = {0.f, 0.f, 0.f, 0.f};
                    #pragma unroll
                    for (int k = 0; k < 4; ++k)
                        acc = __builtin_amdgcn_mfma_f32_16x16x32_bf16(
                                  afrag[ms][k], bfrag[ns][k], acc, 0, 0, 0);
                    const int cl = clab[sub * 2 + ns];
                    #pragma unroll
                    for (int e = 0; e < 4; ++e) {
                        float v = (cl != rlab[ms][e]) ? acc[e] : -4.0f;
                        gmax[ms][e] = fmaxf(gmax[ms][e], v);
                    }
                }
            }
        }

        if (st < 7) {
            // write prefetched stage into the buffer NOT being read this iter.
            // The barrier ending stage st-1 already guaranteed all waves are
            // done reading that buffer.
            const int nxt = cur ^ 1;
            smem[nxt][swz(tid)]       = p0;
            smem[nxt][swz(tid + 256)] = p1;
            smem[nxt][swz(tid + 512)] = p2;
            smem[nxt][swz(tid + 768)] = p3;
            __syncthreads();
        }
    }

    // reduce cols over the 16 lanes of each quad, then atomicMax per row
    #pragma unroll
    for (int s = 0; s < 4; ++s) {
        #pragma unroll
        for (int e = 0; e < 4; ++e) {
            float v = gmax[s][e];
            #pragma unroll
            for (int off = 1; off < 16; off <<= 1)
                v = fmaxf(v, __shfl_xor(v, off));
            if (l15 == 0) {
                int r = rowBase + s * 16 + quad * 4 + e;
                atomicMax(g_ws + r, __float_as_int(2.0f + v));  // keys > 0: int order ok
            }
        }
    }
}

// ---------- kernel 3: final loss + mean ----------
__global__ __launch_bounds__(256) void loss_kernel(
    const float* __restrict__ pos_ws, const int* __restrict__ g_ws,
    float* __restrict__ out)
{
    const int i = blockIdx.x * 256 + threadIdx.x;
    float g    = __int_as_float(g_ws[i]) - 2.0f;
    float neg  = fmaxf(2.0f - 2.0f * g, 0.0f);
    float loss = fmaxf(pos_ws[i] - neg + 0.5f, 0.0f);

    #pragma unroll
    for (int off = 32; off; off >>= 1)
        loss += __shfl_xor(loss, off);

    __shared__ float ws[4];
    if ((threadIdx.x & 63) == 0) ws[threadIdx.x >> 6] = loss;
    __syncthreads();
    if (threadIdx.x == 0) {
        float s = ws[0] + ws[1] + ws[2] + ws[3];
        atomicAdd(out, s * (1.0f / 8192.0f));
    }
}

extern "C" void kernel_launch(void* const* d_in, const int* in_sizes, int n_in,
                              void* d_out, int out_size, void* d_ws, size_t ws_size,
                              hipStream_t stream) {
    const float* anchor   = (const float*)d_in[0];
    const float* positive = (const float*)d_in[1];
    const int*   labels   = (const int*)d_in[2];
    float* out = (float*)d_out;

    char* ws = (char*)d_ws;
    unsigned short* a_hat  = (unsigned short*)ws;                       // 2 MiB
    float*          pos_ws = (float*)(ws + 2 * 1024 * 1024);            // 32 KiB
    int*            g_ws   = (int*)  (ws + 2 * 1024 * 1024 + 32 * 1024);// 32 KiB

    hipMemsetAsync(d_out, 0, sizeof(float), stream);
    normalize_kernel<<<NROWS / 4, 256, 0, stream>>>(anchor, positive, a_hat, pos_ws, g_ws);
    gram_kernel<<<512, 256, 0, stream>>>(a_hat, labels, g_ws);
    loss_kernel<<<NROWS / 256, 256, 0, stream>>>(pos_ws, g_ws, out);
}